// Round 1
// baseline (104.894 us; speedup 1.0000x reference)
//
#include <hip/hip_runtime.h>
#include <hip/hip_bf16.h>
#include <stdint.h>

// Problem constants (B,T,N) = (64,256,64) float32 input, (B,N,N) float32 out.
constexpr int B = 64;
constexpr int T = 256;
constexpr int N = 64;
constexpr int P = (B * (B - 1)) / 2;     // 2016 unordered batch pairs (a<b)
constexpr int WPP = T / 64;              // 4 u64 words per pair (t packed 64/word)
constexpr int NWORDS = P * WPP;          // 8064 words per column bitvector
constexpr int NPAIR_IJ = (N * (N - 1)) / 2;  // 2016 (i<j) column pairs

// ---------------------------------------------------------------------------
// K1: build per-column bitvectors.
//   G[i][w] bit k: x[b, t, i] >  x[a, t, i]
//   Z[i][w] bit k: x[b, t, i] != x[a, t, i]   (tie mask, keeps result exact)
// One block per batch-pair p; 4 waves = 4 t-chunks of 64; lane = column i,
// so each per-t load of 64 lanes is one fully coalesced 256 B transaction.
// ---------------------------------------------------------------------------
__global__ __launch_bounds__(256) void kd_pack(const float* __restrict__ x,
                                               uint64_t* __restrict__ G,
                                               uint64_t* __restrict__ Z) {
    int p = blockIdx.x;
    // decode p -> (a, b) with a < b
    int a = 0, rem = p;
    while (rem >= B - 1 - a) { rem -= B - 1 - a; ++a; }
    int b = a + 1 + rem;

    int wl   = threadIdx.x >> 6;   // t-chunk 0..3
    int lane = threadIdx.x & 63;   // column i
    int t0   = wl * 64;

    const float* xa = x + ((size_t)a * T + t0) * N + lane;
    const float* xb = x + ((size_t)b * T + t0) * N + lane;

    uint64_t g = 0, z = 0;
#pragma unroll
    for (int k = 0; k < 64; ++k) {
        float va = xa[(size_t)k * N];
        float vb = xb[(size_t)k * N];
        g |= (uint64_t)(vb > va)  << k;
        z |= (uint64_t)(vb != va) << k;
    }
    int w = p * WPP + wl;
    G[(size_t)lane * NWORDS + w] = g;
    Z[(size_t)lane * NWORDS + w] = z;
}

// ---------------------------------------------------------------------------
// K2: per (i<j) column pair, C_half = sum_w [ popcnt(zz) - 2*popcnt((gi^gj)&zz) ]
// with zz = Zi&Zj. D[i,j] = 1 - C_half/1008  (since C_ref = 2*C_half,
// pairs = 2016). Block of 256 strides the 8064 words, then block-reduces.
// ---------------------------------------------------------------------------
__global__ __launch_bounds__(256) void kd_gram(const uint64_t* __restrict__ G,
                                               const uint64_t* __restrict__ Z,
                                               float* __restrict__ Dmat) {
    int pidx = blockIdx.x;
    int i = 0, rem = pidx;
    while (rem >= N - 1 - i) { rem -= N - 1 - i; ++i; }
    int j = i + 1 + rem;

    const uint64_t* Gi = G + (size_t)i * NWORDS;
    const uint64_t* Gj = G + (size_t)j * NWORDS;
    const uint64_t* Zi = Z + (size_t)i * NWORDS;
    const uint64_t* Zj = Z + (size_t)j * NWORDS;

    int acc = 0;
    for (int w = threadIdx.x; w < NWORDS; w += 256) {
        uint64_t zz = Zi[w] & Zj[w];
        uint64_t xr = (Gi[w] ^ Gj[w]) & zz;
        acc += __popcll(zz) - 2 * (int)__popcll(xr);
    }

    // wave reduce (64 lanes)
#pragma unroll
    for (int off = 32; off > 0; off >>= 1) acc += __shfl_down(acc, off, 64);

    __shared__ int wsum[4];
    if ((threadIdx.x & 63) == 0) wsum[threadIdx.x >> 6] = acc;
    __syncthreads();
    if (threadIdx.x == 0) {
        int total = wsum[0] + wsum[1] + wsum[2] + wsum[3];
        float d = 1.0f - (float)total * (1.0f / 1008.0f);
        Dmat[i * N + j] = d;
        Dmat[j * N + i] = d;
    }
}

// ---------------------------------------------------------------------------
// K3: broadcast D (64x64) across the B batch slices; diagonal forced to 0
// (Dmat diagonal is never written, and we never read it).
// ---------------------------------------------------------------------------
__global__ __launch_bounds__(256) void kd_bcast(const float* __restrict__ Dmat,
                                                float* __restrict__ out) {
    int idx = blockIdx.x * 256 + threadIdx.x;   // 0 .. B*N*N-1
    int ij = idx & (N * N - 1);
    int i = ij >> 6, j = ij & 63;
    out[idx] = (i == j) ? 0.0f : Dmat[ij];
}

extern "C" void kernel_launch(void* const* d_in, const int* in_sizes, int n_in,
                              void* d_out, int out_size, void* d_ws, size_t ws_size,
                              hipStream_t stream) {
    const float* x = (const float*)d_in[0];
    float* out = (float*)d_out;

    // Workspace layout (8.27 MB total):
    //   G:    N * NWORDS u64  = 4,128,768 B
    //   Z:    N * NWORDS u64  = 4,128,768 B
    //   Dmat: N * N float     = 16,384 B
    uint64_t* G = (uint64_t*)d_ws;
    uint64_t* Z = G + (size_t)N * NWORDS;
    float* Dmat = (float*)(Z + (size_t)N * NWORDS);

    kd_pack<<<P, 256, 0, stream>>>(x, G, Z);
    kd_gram<<<NPAIR_IJ, 256, 0, stream>>>(G, Z, Dmat);
    kd_bcast<<<(B * N * N) / 256, 256, 0, stream>>>(Dmat, out);
}

// Round 2
// 98.968 us; speedup vs baseline: 1.0599x; 1.0599x over previous
//
#include <hip/hip_runtime.h>
#include <hip/hip_bf16.h>
#include <stdint.h>

// Problem constants (B,T,N) = (64,256,64) float32 input, (B,N,N) float32 out.
constexpr int B = 64;
constexpr int T = 256;
constexpr int N = 64;
constexpr int P = (B * (B - 1)) / 2;     // 2016 unordered batch pairs (a<b)
constexpr int WPP = T / 64;              // 4 u64 words per pair (t packed 64/word)
constexpr int NWORDS = P * WPP;          // 8064 words per column bitvector
constexpr int W = 16;                    // words per K2 chunk
constexpr int NCHUNK = NWORDS / W;       // 504 chunks

// ---------------------------------------------------------------------------
// K1: build bitvectors, TRANSPOSED layout G[w][col] so K2 can stage whole
// 64-column word-rows contiguously.
//   G[w][i] bit k: x[b, t, i] >  x[a, t, i]
//   Z[w][i] bit k: x[b, t, i] != x[a, t, i]   (tie mask, keeps result exact)
// One block per batch-pair p; 4 waves = 4 t-chunks of 64; lane = column i,
// so loads (256 B/wave) and stores (512 B/wave) are fully coalesced.
// ---------------------------------------------------------------------------
__global__ __launch_bounds__(256) void kd_pack(const float* __restrict__ x,
                                               uint64_t* __restrict__ G,
                                               uint64_t* __restrict__ Z) {
    int p = blockIdx.x;
    int a = 0, rem = p;
    while (rem >= B - 1 - a) { rem -= B - 1 - a; ++a; }
    int b = a + 1 + rem;

    int wl   = threadIdx.x >> 6;   // t-chunk 0..3
    int lane = threadIdx.x & 63;   // column i
    int t0   = wl * 64;

    const float* xa = x + ((size_t)a * T + t0) * N + lane;
    const float* xb = x + ((size_t)b * T + t0) * N + lane;

    uint64_t g = 0, z = 0;
#pragma unroll
    for (int k = 0; k < 64; ++k) {
        float va = xa[(size_t)k * N];
        float vb = xb[(size_t)k * N];
        g |= (uint64_t)(vb > va)  << k;
        z |= (uint64_t)(vb != va) << k;
    }
    int w = p * WPP + wl;
    G[(size_t)w * N + lane] = g;
    Z[(size_t)w * N + lane] = z;
}

// ---------------------------------------------------------------------------
// K2: Gram over words, tiled. Block = one 16-word chunk: stage G/Z rows into
// LDS (16 KB), thread (gi,gj) = (tid>>4, tid&15) computes a 4x4 column-pair
// tile in registers, writes 16 int partials to part[chunk][i*64+j].
// Full 64x64 computed (incl. i==j, fixed up later) — each word read from
// global exactly once: K2 global traffic = 8.3 MB total.
// ---------------------------------------------------------------------------
__global__ __launch_bounds__(256) void kd_gram(const uint64_t* __restrict__ G,
                                               const uint64_t* __restrict__ Z,
                                               int* __restrict__ part) {
    __shared__ uint64_t LG[W * 64];
    __shared__ uint64_t LZ[W * 64];
    int tid = threadIdx.x;
    int chunk = blockIdx.x;
    size_t base = (size_t)chunk * W * 64;

    const ulonglong2* Gg = (const ulonglong2*)(G + base);
    const ulonglong2* Zg = (const ulonglong2*)(Z + base);
    ulonglong2* LG2 = (ulonglong2*)LG;
    ulonglong2* LZ2 = (ulonglong2*)LZ;
    LG2[tid]       = Gg[tid];
    LG2[tid + 256] = Gg[tid + 256];
    LZ2[tid]       = Zg[tid];
    LZ2[tid + 256] = Zg[tid + 256];
    __syncthreads();

    int i0 = (tid >> 4) * 4;
    int j0 = (tid & 15) * 4;
    int acc[4][4] = {};

#pragma unroll 2
    for (int w = 0; w < W; ++w) {
        uint64_t gi[4], zi[4], gj[4], zj[4];
#pragma unroll
        for (int u = 0; u < 4; ++u) {
            gi[u] = LG[w * 64 + i0 + u];
            zi[u] = LZ[w * 64 + i0 + u];
            gj[u] = LG[w * 64 + j0 + u];
            zj[u] = LZ[w * 64 + j0 + u];
        }
#pragma unroll
        for (int u = 0; u < 4; ++u)
#pragma unroll
            for (int v = 0; v < 4; ++v) {
                uint64_t zz = zi[u] & zj[v];
                uint64_t xr = (gi[u] ^ gj[v]) & zz;
                acc[u][v] += (int)__popcll(zz) - 2 * (int)__popcll(xr);
            }
    }

    int* po = part + (size_t)chunk * (N * N);
#pragma unroll
    for (int u = 0; u < 4; ++u)
#pragma unroll
        for (int v = 0; v < 4; ++v)
            po[(i0 + u) * N + (j0 + v)] = acc[u][v];
}

// ---------------------------------------------------------------------------
// K3: fold the 504 partial Gram tiles into Dmat. C_ref = 2*C_half (a<b only),
// pairs = 2016 -> D = 1 - C_half/1008. Diagonal cells hold garbage-but-finite
// values; K4 forces them to 0.
// ---------------------------------------------------------------------------
__global__ __launch_bounds__(256) void kd_reduce(const int* __restrict__ part,
                                                 float* __restrict__ Dmat) {
    int cell = blockIdx.x * 256 + threadIdx.x;   // 0..4095
    int total = 0;
    for (int c = 0; c < NCHUNK; ++c) total += part[(size_t)c * (N * N) + cell];
    Dmat[cell] = 1.0f - (float)total * (1.0f / 1008.0f);
}

// ---------------------------------------------------------------------------
// K4: broadcast D (64x64) across the B batch slices; diagonal forced to 0.
// ---------------------------------------------------------------------------
__global__ __launch_bounds__(256) void kd_bcast(const float* __restrict__ Dmat,
                                                float* __restrict__ out) {
    int idx = blockIdx.x * 256 + threadIdx.x;    // 0 .. B*N*N-1
    int ij = idx & (N * N - 1);
    int i = ij >> 6, j = ij & 63;
    out[idx] = (i == j) ? 0.0f : Dmat[ij];
}

extern "C" void kernel_launch(void* const* d_in, const int* in_sizes, int n_in,
                              void* d_out, int out_size, void* d_ws, size_t ws_size,
                              hipStream_t stream) {
    const float* x = (const float*)d_in[0];
    float* out = (float*)d_out;

    // Workspace layout (~16.5 MB):
    //   G:    NWORDS * N u64 = 4,128,768 B
    //   Z:    NWORDS * N u64 = 4,128,768 B
    //   part: NCHUNK * 4096 int = 8,257,536 B
    //   Dmat: 4096 float = 16,384 B
    uint64_t* G = (uint64_t*)d_ws;
    uint64_t* Z = G + (size_t)NWORDS * N;
    int* part = (int*)(Z + (size_t)NWORDS * N);
    float* Dmat = (float*)(part + (size_t)NCHUNK * (N * N));

    kd_pack<<<P, 256, 0, stream>>>(x, G, Z);
    kd_gram<<<NCHUNK, 256, 0, stream>>>(G, Z, part);
    kd_reduce<<<(N * N) / 256, 256, 0, stream>>>(part, Dmat);
    kd_bcast<<<(B * N * N) / 256, 256, 0, stream>>>(Dmat, out);
}

// Round 3
// 93.180 us; speedup vs baseline: 1.1257x; 1.0621x over previous
//
#include <hip/hip_runtime.h>
#include <stdint.h>

// (B,T,N) = (64,256,64) f32 input, (B,N,N) f32 out.
// Rotation formulation: for fixed (t,i), lanes hold x[a,t,i] (a = lane).
// For d=1..31: word_d bit a = [x[(a+d)%64,t,i] > x[a,t,i]]  -> 64 distinct
// unordered batch pairs each; d=32 masked to low 32 bits -> 32 pairs.
// Total 2016 pair-slots per (t,i). With no ties, s_i*s_j = 1-2*(g_i^g_j), so
// C_half[i,j] = 516096 - 2*X[i,j],  X = sum_w popcnt(Gi^Gj),
// D = 1 - C_half/1008 = X/504 - 511.  (A tie costs 1e-3 << 0.22 threshold.)
constexpr int B = 64, T = 256, N = 64;
constexpr int DW = 32;            // words per (t,i): d = 1..32
constexpr int WPC = T * DW;       // 8192 words per column
constexpr int SRC = 512;          // K2 partial count (t x d-half)

// ---------------------------------------------------------------------------
// K1: grid 1024 = (t, i-quarter), block 256. LDS-transpose x[.][t][.] then
// ballot-pack. Input traffic 4x4.2 MB coalesced; writes 4 MiB of G words.
// Layout: G[i*WPC + t*32 + (d-1)].
// ---------------------------------------------------------------------------
__global__ __launch_bounds__(256) void kd_pack(const float* __restrict__ x,
                                               uint64_t* __restrict__ G) {
    __shared__ float V[64 * 65];          // V[a][i], pad 65: (lane+i)%32 banks
    int t  = blockIdx.x >> 2;
    int iq = blockIdx.x & 3;
    int tid = threadIdx.x;
    {
        int a = tid >> 2, seg = tid & 3;  // 4 lanes per batch row
        const float4* xg = (const float4*)x;
        size_t base = ((size_t)a * T + t) * (N / 4);
#pragma unroll
        for (int s = 0; s < 4; ++s) {
            float4 v4 = xg[base + seg * 4 + s];
            int off = a * 65 + seg * 16 + s * 4;
            V[off + 0] = v4.x; V[off + 1] = v4.y;
            V[off + 2] = v4.z; V[off + 3] = v4.w;
        }
    }
    __syncthreads();

    int w = tid >> 6, lane = tid & 63;
#pragma unroll
    for (int ii = 0; ii < 4; ++ii) {
        int i = iq * 16 + w * 4 + ii;
        float v = V[lane * 65 + i];
        uint64_t wv = 0;
#pragma unroll
        for (int d = 1; d <= 32; ++d) {
            float vr = __shfl(v, (lane + d) & 63, 64);
            uint64_t m = __ballot(vr > v);
            if (d == 32) m &= 0xffffffffull;     // upper 32 = duplicate pairs
            if (lane == d - 1) wv = m;           // word for this d -> lane d-1
        }
        if (lane < 32)
            G[(size_t)i * WPC + t * DW + lane] = wv;   // 256 B coalesced
    }
}

// ---------------------------------------------------------------------------
// K2: grid 512 = (t, d-half), block 256. Stage G-words for 16 d x 64 i into
// LDS (8.4 KB, [d][i] stride 66 for aligned ulonglong2 reads), 4x4 register
// tile per thread, X-partials to part[block][4096].
// ---------------------------------------------------------------------------
__global__ __launch_bounds__(256) void kd_gram(const uint64_t* __restrict__ G,
                                               int* __restrict__ part) {
    __shared__ uint64_t LG[16 * 66];
    int t = blockIdx.x >> 1, dh = blockIdx.x & 1;
    int tid = threadIdx.x;
    int base = t * DW + dh * 16;
    {
        int i = tid >> 2, k = tid & 3;    // 4 lanes x 32 B per column row
        const ulonglong2* gp = (const ulonglong2*)(G + (size_t)i * WPC + base);
        ulonglong2 v0 = gp[k * 2], v1 = gp[k * 2 + 1];
        LG[(4 * k + 0) * 66 + i] = v0.x;
        LG[(4 * k + 1) * 66 + i] = v0.y;
        LG[(4 * k + 2) * 66 + i] = v1.x;
        LG[(4 * k + 3) * 66 + i] = v1.y;
    }
    __syncthreads();

    const ulonglong2* LGv = (const ulonglong2*)LG;   // 33 vec2 per d-row
    int i0 = (tid >> 4) * 4, j0 = (tid & 15) * 4;
    int acc[4][4] = {};
#pragma unroll
    for (int d = 0; d < 16; ++d) {
        ulonglong2 A0 = LGv[d * 33 + (i0 >> 1)];
        ulonglong2 A1 = LGv[d * 33 + (i0 >> 1) + 1];
        ulonglong2 B0 = LGv[d * 33 + (j0 >> 1)];
        ulonglong2 B1 = LGv[d * 33 + (j0 >> 1) + 1];
        uint64_t gi[4] = {A0.x, A0.y, A1.x, A1.y};
        uint64_t gj[4] = {B0.x, B0.y, B1.x, B1.y};
#pragma unroll
        for (int u = 0; u < 4; ++u)
#pragma unroll
            for (int v = 0; v < 4; ++v)
                acc[u][v] += (int)__popcll(gi[u] ^ gj[v]);
    }
    int* po = part + (size_t)blockIdx.x * (N * N);
#pragma unroll
    for (int u = 0; u < 4; ++u)
#pragma unroll
        for (int v = 0; v < 4; ++v)
            po[(i0 + u) * N + (j0 + v)] = acc[u][v];
}

// ---------------------------------------------------------------------------
// K3: fold 512 partials -> Dmat. grid 64 blocks x 256 thr:
// block b owns 64 cells; 4 src-groups strided, LDS-folded.
// ---------------------------------------------------------------------------
__global__ __launch_bounds__(256) void kd_reduce(const int* __restrict__ part,
                                                 float* __restrict__ Dmat) {
    __shared__ int R[4][64];
    int b = blockIdx.x, tid = threadIdx.x;
    int c = b * 64 + (tid & 63);
    int sg = tid >> 6;
    int acc = 0;
    for (int s = sg; s < SRC; s += 4)
        acc += part[(size_t)s * (N * N) + c];
    R[sg][tid & 63] = acc;
    __syncthreads();
    if (tid < 64) {
        int X = R[0][tid] + R[1][tid] + R[2][tid] + R[3][tid];
        Dmat[b * 64 + tid] = (float)X * (1.0f / 504.0f) - 511.0f;
    }
}

// ---------------------------------------------------------------------------
// K4: broadcast D over batch; diagonal = 0.
// ---------------------------------------------------------------------------
__global__ __launch_bounds__(256) void kd_bcast(const float* __restrict__ Dmat,
                                                float* __restrict__ out) {
    int idx = blockIdx.x * 256 + threadIdx.x;
    int ij = idx & (N * N - 1);
    int i = ij >> 6, j = ij & 63;
    out[idx] = (i == j) ? 0.0f : Dmat[ij];
}

extern "C" void kernel_launch(void* const* d_in, const int* in_sizes, int n_in,
                              void* d_out, int out_size, void* d_ws, size_t ws_size,
                              hipStream_t stream) {
    const float* x = (const float*)d_in[0];
    float* out = (float*)d_out;

    // ws: G 4 MiB | part 8 MiB | Dmat 16 KB
    uint64_t* G = (uint64_t*)d_ws;
    int* part = (int*)(G + (size_t)N * WPC);
    float* Dmat = (float*)(part + (size_t)SRC * (N * N));

    kd_pack<<<T * 4, 256, 0, stream>>>(x, G);
    kd_gram<<<SRC, 256, 0, stream>>>(G, part);
    kd_reduce<<<64, 256, 0, stream>>>(part, Dmat);
    kd_bcast<<<(B * N * N) / 256, 256, 0, stream>>>(Dmat, out);
}

// Round 4
// 82.537 us; speedup vs baseline: 1.2709x; 1.1289x over previous
//
#include <hip/hip_runtime.h>
#include <stdint.h>

// (B,T,N) = (64,256,64) f32 input, (B,N,N) f32 out.
// Rotation formulation, no ties (inputs are continuous f32 normals; a tie
// perturbs D by ~1e-3 << 0.22 threshold):
//   word(t,i,d) bit a = [x[(a+d)%64, t, i] > x[a, t, i]],  d = 1..31 full,
//   d = 32 masked to low 32 bits -> 2016 distinct unordered batch pairs.
//   X[i,j] = sum_words popcnt(Gi ^ Gj);  D = X/504 - 511.
constexpr int B = 64, T = 256, N = 64;
constexpr int NPART = T * 2;      // (t, d-half) partials

// ---------------------------------------------------------------------------
// K1: fused pack+gram. Grid 256 (= t), block 512 (8 waves).
// Phase B (pack): lane = column i, wave w owns d = 4w+1 .. 4w+4. Thread loads
//   r[a] = x[a,t,i] and s[a] = x[(a+4w)&63, t, i]  (both coalesced 256 B/inst,
//   L2-resident). Then bit a of word d=4w+k+1 is s[(a+k+1)&63] > r[a] — all
//   register indices compile-time static: pure VALU, zero bpermute/shfl.
//   Words -> LDS LG[dslot][i] (stride 66 u64: aligned ulonglong2, no 4-way).
// Phase C (gram): 512 thr = 2 d-halves x (16x16 thread grid), 4x4 register
//   tile per thread, 4 ulonglong2 LDS reads per d per 16 cells.
//   Partials -> part[(t,half)][4096].
// ---------------------------------------------------------------------------
__global__ __launch_bounds__(512) void kd_fused(const float* __restrict__ x,
                                                int* __restrict__ part) {
    __shared__ uint64_t LG[32 * 66];
    int t = blockIdx.x;
    int tid = threadIdx.x;
    int lane = tid & 63;          // column i
    int w    = tid >> 6;          // wave 0..7
    int rot  = w * 4;

    // ---- Phase B: build the 32 G-words for this t ----
    {
        const float* xb = x + (size_t)t * N + lane;
        float r[64], s[64];
#pragma unroll
        for (int a = 0; a < 64; ++a)
            r[a] = xb[(size_t)a * (T * N)];
#pragma unroll
        for (int a = 0; a < 64; ++a)
            s[a] = xb[(size_t)((a + rot) & 63) * (T * N)];

#pragma unroll
        for (int k = 0; k < 4; ++k) {
            // d = rot + k + 1 ; bit a: x[(a+d)&63] > x[a]
            uint64_t gw = 0;
#pragma unroll
            for (int a = 0; a < 64; ++a)
                gw |= (uint64_t)(s[(a + k + 1) & 63] > r[a]) << a;
            int dslot = rot + k;                  // 0..31
            if (dslot == 31) gw &= 0xffffffffull; // d=32: upper 32 duplicate
            LG[dslot * 66 + lane] = gw;
        }
    }
    __syncthreads();

    // ---- Phase C: Gram for this t ----
    int half = tid >> 8;                    // 0,1 -> d 0..15 / 16..31
    int t2 = tid & 255;
    int i0 = (t2 >> 4) * 4, j0 = (t2 & 15) * 4;
    const ulonglong2* LGv = (const ulonglong2*)LG;   // 33 vec2 per d-row
    int acc[4][4] = {};
#pragma unroll
    for (int dd = 0; dd < 16; ++dd) {
        int d = half * 16 + dd;
        ulonglong2 A0 = LGv[d * 33 + (i0 >> 1)];
        ulonglong2 A1 = LGv[d * 33 + (i0 >> 1) + 1];
        ulonglong2 B0 = LGv[d * 33 + (j0 >> 1)];
        ulonglong2 B1 = LGv[d * 33 + (j0 >> 1) + 1];
        uint64_t gi[4] = {A0.x, A0.y, A1.x, A1.y};
        uint64_t gj[4] = {B0.x, B0.y, B1.x, B1.y};
#pragma unroll
        for (int u = 0; u < 4; ++u)
#pragma unroll
            for (int v = 0; v < 4; ++v)
                acc[u][v] += (int)__popcll(gi[u] ^ gj[v]);
    }
    int* po = part + ((size_t)t * 2 + half) * (N * N);
#pragma unroll
    for (int u = 0; u < 4; ++u)
#pragma unroll
        for (int v = 0; v < 4; ++v)
            po[(i0 + u) * N + (j0 + v)] = acc[u][v];
}

// ---------------------------------------------------------------------------
// K2: fold 512 partials -> D, broadcast over batch, diagonal = 0.
// Grid 64 (cell-group b = row i), block 256. Block b's cells are i=b, j=0..63,
// so the diagonal cell is l == b.
// ---------------------------------------------------------------------------
__global__ __launch_bounds__(256) void kd_out(const int* __restrict__ part,
                                              float* __restrict__ out) {
    __shared__ int R[4][64];
    __shared__ float Dv[64];
    int b = blockIdx.x, tid = threadIdx.x;
    int l = tid & 63, sg = tid >> 6;
    int acc = 0;
    for (int s = sg; s < NPART; s += 4)
        acc += part[(size_t)s * (N * N) + b * 64 + l];
    R[sg][l] = acc;
    __syncthreads();
    if (tid < 64) {
        int X = R[0][tid] + R[1][tid] + R[2][tid] + R[3][tid];
        Dv[tid] = (tid == b) ? 0.0f : ((float)X * (1.0f / 504.0f) - 511.0f);
    }
    __syncthreads();
#pragma unroll
    for (int it = 0; it < 16; ++it) {
        int batch = it * 4 + sg;
        out[(size_t)batch * (N * N) + b * 64 + l] = Dv[l];
    }
}

extern "C" void kernel_launch(void* const* d_in, const int* in_sizes, int n_in,
                              void* d_out, int out_size, void* d_ws, size_t ws_size,
                              hipStream_t stream) {
    const float* x = (const float*)d_in[0];
    float* out = (float*)d_out;

    // ws: part = 512 * 4096 int = 8 MiB
    int* part = (int*)d_ws;

    kd_fused<<<T, 512, 0, stream>>>(x, part);
    kd_out<<<N, 256, 0, stream>>>(part, out);
}